// Round 2
// baseline (10636.673 us; speedup 1.0000x reference)
//
#include <hip/hip_runtime.h>
#include <stdint.h>

// PaddGRULayer: B=256, T=512, F=64, U=128. fp32 in/out (reference dtype).
// One persistent block per batch row (256 blocks x 256 threads, 1 block/CU).
// Weights register-resident as packed bf16 pairs (fp32->bf16 at load); state fp32 in LDS.

#define T_STEPS 512
#define BDIM 256

typedef unsigned int u32;
typedef unsigned short u16;

__device__ __forceinline__ u16 f2bf(float f) {
    u32 u = __float_as_uint(f);
    u32 r = (u + 0x7fffu + ((u >> 16) & 1u)) >> 16;  // RNE
    return (u16)r;
}
__device__ __forceinline__ u32 pack2(float a, float b) {
    return (u32)f2bf(a) | ((u32)f2bf(b) << 16);
}
__device__ __forceinline__ float lo_f(u32 u) { return __uint_as_float(u << 16); }
__device__ __forceinline__ float hi_f(u32 u) { return __uint_as_float(u & 0xffff0000u); }
__device__ __forceinline__ float sigm(float x) { return 1.0f / (1.0f + __expf(-x)); }
__device__ __forceinline__ float tanh_f(float x) { return 2.0f / (1.0f + __expf(-2.0f * x)) - 1.0f; }

__global__ __launch_bounds__(BDIM, 1)
void padd_gru_kernel(
    const float* __restrict__ xin,                       // [256,512,320]
    const float* __restrict__ h0,                        // [256,128]
    const float* __restrict__ ts0,                       // [256,64]
    const float* __restrict__ dt0,                       // [256,64]
    const float* __restrict__ w_reg, const float* __restrict__ b_reg,   // [128,64],[1]
    const float* __restrict__ w_ctl, const float* __restrict__ b_ctl,   // [128,64],[64]
    const float* __restrict__ w_dlt, const float* __restrict__ b_dlt,   // [64,128],[1]
    const float* __restrict__ w_vm,  const float* __restrict__ b_vm,    // [128,128],[1]
    const float* __restrict__ w_cor, const float* __restrict__ b_cor,   // [64,64],[64]
    const float* __restrict__ w_cat, const float* __restrict__ b_cat,   // [192,64],[1]
    const float* __restrict__ u_upd, const float* __restrict__ w_upd, const float* __restrict__ b_upd, // [128,128]x2,[1]
    const float* __restrict__ u_rst, const float* __restrict__ w_rst, const float* __restrict__ b_rst, // [128,128]x2,[1]
    float* __restrict__ out)
{
    const int t = threadIdx.x;
    const int b = blockIdx.x;

    __shared__ float h32[128];
    __shared__ float outbuf[320];   // [xreg(64) | zcorr(64) | c(64) | ts(64) | dt(64)] = output row order
    __shared__ float tv32[64];
    __shared__ float xcur32[64];
    __shared__ float cat32[192];    // [m(64) | decay(128)]  (stage D input)
    __shared__ float inE32[256];    // [dh(128) | c(64) | m(64)]  (stage E input)
    __shared__ float rdh32[128];
    __shared__ float zr[256];
    __shared__ float red[256];
    __shared__ float red2[256];
    __shared__ float xs[320];
    __shared__ float bctl32[64];
    __shared__ float bcor32[64];

    const int jA  = t & 127, sgA = t >> 7;   // stage A / C1 / F mapping (wave-uniform sgA)
    const int j4  = t & 63,  sg4 = t >> 6;   // stage C2 / D mapping (wave-uniform sg4)

    // -------- register-resident packed-bf16 weights (converted from fp32) --------
    u32 wA[32];    // [w_reg | w_ctl] col jA, k in [64*sgA, 64*sgA+64)
    u32 wD[16];    // w_delta col jA, k in [32*sgA, +32)
    u32 wC[8];     // w_corr (diag-masked) col j4, k in [16*sg4, +16)
    u32 wCt[24];   // w_concat col j4, k in [48*sg4, +48)
    u32 wE[128];   // t<128: [u_upd; w_upd] col t ; t>=128: [u_rst; w_rst] col t-128  (full K=256)
    u32 wF[64];    // sgA==0: u_upd col jA (k<128) ; sgA==1: w_value_mask col jA (k-128)

    {
        const float* src = (jA < 64) ? (w_reg + jA) : (w_ctl + (jA - 64));
        #pragma unroll
        for (int i = 0; i < 32; i++) {
            int k = 64 * sgA + 2 * i;
            wA[i] = pack2(src[k * 64], src[(k + 1) * 64]);
        }
    }
    {
        #pragma unroll
        for (int i = 0; i < 16; i++) {
            int k = 32 * sgA + 2 * i;
            wD[i] = pack2(w_dlt[k * 128 + jA], w_dlt[(k + 1) * 128 + jA]);
        }
    }
    {
        #pragma unroll
        for (int i = 0; i < 8; i++) {
            int k = 16 * sg4 + 2 * i;
            float a = (k     == j4) ? 0.f : w_cor[k * 64 + j4];
            float c = (k + 1 == j4) ? 0.f : w_cor[(k + 1) * 64 + j4];
            wC[i] = pack2(a, c);
        }
    }
    {
        #pragma unroll
        for (int i = 0; i < 24; i++) {
            int k = 48 * sg4 + 2 * i;
            wCt[i] = pack2(w_cat[k * 64 + j4], w_cat[(k + 1) * 64 + j4]);
        }
    }
    {
        const float* s1 = (t < 128) ? (u_upd + jA) : (u_rst + jA);
        const float* s2 = (t < 128) ? (w_upd + jA) : (w_rst + jA);
        #pragma unroll
        for (int i = 0; i < 64; i++) {
            int k = 2 * i;
            wE[i]      = pack2(s1[k * 128], s1[(k + 1) * 128]);
            wE[64 + i] = pack2(s2[k * 128], s2[(k + 1) * 128]);
        }
        const float* s3 = (sgA == 0) ? (u_upd + jA) : (w_vm + jA);
        #pragma unroll
        for (int i = 0; i < 64; i++) {
            int k = 2 * i;
            wF[i] = pack2(s3[k * 128], s3[(k + 1) * 128]);
        }
    }

    const float bReg = b_reg[0];
    const float bDlt = b_dlt[0];
    const float bVm  = b_vm[0];
    const float bCat = b_cat[0];
    const float bUpd = b_upd[0];
    const float bRst = b_rst[0];

    if (t < 128) h32[t] = h0[(size_t)b * 128 + t];
    if (t < 64) {
        outbuf[192 + t] = ts0[(size_t)b * 64 + t];
        outbuf[256 + t] = dt0[(size_t)b * 64 + t];
        bctl32[t] = b_ctl[t];
        bcor32[t] = b_cor[t];
    }
    __syncthreads();

    float zloc = 0.0f;  // z gate, persists E-combine -> F-combine (same thread t<128)

    for (int st = 0; st < T_STEPS; ++st) {
        // input row -> LDS (coalesced float2 loads)
        {
            const float2* xr = (const float2*)(xin + ((size_t)b * 512 + st) * 320);
            if (t < 160) {
                float2 v = xr[t];
                xs[2 * t]     = v.x;
                xs[2 * t + 1] = v.y;
            }
        }

        // ---- stage A: h @ [w_reg | w_ctl]  (K=128 -> N=128, 2-way k-split)
        {
            float a0 = 0.f, a1 = 0.f;
            const float* hp = &h32[64 * sgA];
            #pragma unroll
            for (int i = 0; i < 32; i++) {
                u32 u = wA[i];
                a0 = fmaf(lo_f(u), hp[2 * i],     a0);
                a1 = fmaf(hi_f(u), hp[2 * i + 1], a1);
            }
            red[t] = a0 + a1;
        }
        __syncthreads();  // B1
        if (t < 128) {
            float s = red[t] + red[t + 128];
            if (t < 64) outbuf[t] = s + bReg;                  // x_reg
            else        tv32[t - 64] = fabsf(s + bctl32[t - 64]); // tv
        }
        __syncthreads();  // B2

        // ---- phase 2: elementwise ti/dt/x_cur (t<64)
        if (t < 64) {
            float ti_in = xs[t], x_in = xs[64 + t], m = xs[128 + t];
            float dt_in = xs[192 + t], pad = xs[256 + t];
            float pts = outbuf[192 + t], pdt = outbuf[256 + t];
            float tv = tv32[t], xrg = outbuf[t];
            float s   = pts + tv;
            float tic = pad * ti_in + (1.f - pad) * s;
            float tin = (tic <= 100.0f) ? tic : pts;
            float dg  = (s <= 100.0f) ? tv : pdt;
            float dtn = pad * dt_in + (1.f - pad) * dg;
            float xc  = m * x_in + (1.f - m) * xrg;
            outbuf[192 + t] = tin;   // ts (also output slice 3)
            outbuf[256 + t] = dtn;   // dt (also output slice 4)
            xcur32[t] = xc;
            cat32[t] = m;
            inE32[192 + t] = m;
        }
        __syncthreads();  // B3

        // ---- stage C: decay-pre (dt @ w_delta) and z_corr (x_cur @ w_corr_masked)
        {
            float a0 = 0.f, a1 = 0.f;
            const float* dp = &outbuf[256 + 32 * sgA];
            #pragma unroll
            for (int i = 0; i < 16; i++) {
                u32 u = wD[i];
                a0 = fmaf(lo_f(u), dp[2 * i],     a0);
                a1 = fmaf(hi_f(u), dp[2 * i + 1], a1);
            }
            red[t] = a0 + a1;
            float c0 = 0.f, c1 = 0.f;
            const float* xp = &xcur32[16 * sg4];
            #pragma unroll
            for (int i = 0; i < 8; i++) {
                u32 u = wC[i];
                c0 = fmaf(lo_f(u), xp[2 * i],     c0);
                c1 = fmaf(hi_f(u), xp[2 * i + 1], c1);
            }
            red2[t] = c0 + c1;
        }
        __syncthreads();  // B4
        if (t < 128) {
            float pre = red[t] + red[t + 128] + bDlt;
            float d = __expf(-fmaxf(pre, 0.f));     // decay
            cat32[64 + t] = d;
            inE32[t] = d * h32[t];                  // dh
            if (t < 64) {
                float zc = red2[t] + red2[64 + t] + red2[128 + t] + red2[192 + t] + bcor32[t];
                outbuf[64 + t] = zc;                // z_corr
            }
        }
        __syncthreads();  // B5

        // ---- stage D: beta-pre = [m, decay] @ w_concat (K=192 -> N=64, 4-way split)
        {
            float a0 = 0.f, a1 = 0.f;
            const float* cp = &cat32[48 * sg4];
            #pragma unroll
            for (int i = 0; i < 24; i++) {
                u32 u = wCt[i];
                a0 = fmaf(lo_f(u), cp[2 * i],     a0);
                a1 = fmaf(hi_f(u), cp[2 * i + 1], a1);
            }
            red[t] = a0 + a1;
        }
        __syncthreads();  // B6
        if (t < 64) {
            float pre  = red[t] + red[64 + t] + red[128 + t] + red[192 + t] + bCat;
            float beta = sigm(pre);
            float ct   = beta * outbuf[64 + t] + (1.f - beta) * outbuf[t];
            float m    = inE32[192 + t];
            float c    = m * xcur32[t] + (1.f - m) * ct;
            outbuf[128 + t] = c;
            inE32[128 + t]  = c;
        }
        __syncthreads();  // B7

        // ---- stage E: [dh|c|m](256) @ [[u_upd,u_rst],[w_upd,w_rst]]  (col j=t, full K, no reduce)
        {
            float a0 = 0.f, a1 = 0.f, a2 = 0.f, a3 = 0.f;
            #pragma unroll
            for (int i = 0; i < 128; i += 2) {
                u32 u = wE[i], v = wE[i + 1];
                a0 = fmaf(lo_f(u), inE32[2 * i],     a0);
                a1 = fmaf(hi_f(u), inE32[2 * i + 1], a1);
                a2 = fmaf(lo_f(v), inE32[2 * i + 2], a2);
                a3 = fmaf(hi_f(v), inE32[2 * i + 3], a3);
            }
            zr[t] = (a0 + a1) + (a2 + a3);
        }
        __syncthreads();  // B8
        // ---- E combine: z (kept in reg), r -> r*dh ; plus output row store
        if (t < 128) {
            zloc = sigm(zr[t] + bUpd);
        } else {
            float r = sigm(zr[t] + bRst);
            rdh32[t - 128] = r * inE32[t - 128];
        }
        if (t < 160) {
            float2 v;
            v.x = outbuf[2 * t];
            v.y = outbuf[2 * t + 1];
            float2* orow = (float2*)(out + ((size_t)st * 256 + b) * 320);
            orow[t] = v;
        }
        __syncthreads();  // B9

        // ---- stage F: [r*dh | c | m](256) @ [u_upd ; w_value_mask] (N=128, 2-way split)
        {
            float a0 = 0.f, a1 = 0.f, a2 = 0.f, a3 = 0.f;
            const float* fp = (sgA == 0) ? rdh32 : &inE32[128];
            #pragma unroll
            for (int i = 0; i < 64; i += 2) {
                u32 u = wF[i], v = wF[i + 1];
                a0 = fmaf(lo_f(u), fp[2 * i],     a0);
                a1 = fmaf(hi_f(u), fp[2 * i + 1], a1);
                a2 = fmaf(lo_f(v), fp[2 * i + 2], a2);
                a3 = fmaf(hi_f(v), fp[2 * i + 3], a3);
            }
            red[t] = (a0 + a1) + (a2 + a3);
        }
        __syncthreads();  // B10
        if (t < 128) {
            float hh = tanh_f(red[t] + red[128 + t] + bVm);
            h32[t] = (1.f - zloc) * h32[t] + zloc * hh;
        }
        __syncthreads();  // B11
    }

    // final carry outputs: hT, tsT, dtT
    if (t < 128) out[(size_t)41943040u + (size_t)b * 128 + t] = h32[t];
    if (t < 64) {
        out[(size_t)41975808u + (size_t)b * 64 + t] = outbuf[192 + t];
        out[(size_t)41992192u + (size_t)b * 64 + t] = outbuf[256 + t];
    }
}

extern "C" void kernel_launch(void* const* d_in, const int* in_sizes, int n_in,
                              void* d_out, int out_size, void* d_ws, size_t ws_size,
                              hipStream_t stream) {
    const float* xin   = (const float*)d_in[0];
    const float* h0    = (const float*)d_in[1];
    const float* ts0   = (const float*)d_in[2];
    const float* dt0   = (const float*)d_in[3];
    const float* w_reg = (const float*)d_in[4];
    const float* b_reg = (const float*)d_in[5];
    const float* w_ctl = (const float*)d_in[6];
    const float* b_ctl = (const float*)d_in[7];
    const float* w_dlt = (const float*)d_in[8];
    const float* b_dlt = (const float*)d_in[9];
    const float* w_vm  = (const float*)d_in[10];
    const float* b_vm  = (const float*)d_in[11];
    const float* w_cor = (const float*)d_in[12];
    const float* b_cor = (const float*)d_in[13];
    const float* w_cat = (const float*)d_in[14];
    const float* b_cat = (const float*)d_in[15];
    const float* u_upd = (const float*)d_in[16];
    const float* w_upd = (const float*)d_in[17];
    const float* b_upd = (const float*)d_in[18];
    const float* u_rst = (const float*)d_in[19];
    const float* w_rst = (const float*)d_in[20];
    const float* b_rst = (const float*)d_in[21];

    padd_gru_kernel<<<dim3(256), dim3(BDIM), 0, stream>>>(
        xin, h0, ts0, dt0,
        w_reg, b_reg, w_ctl, b_ctl, w_dlt, b_dlt, w_vm, b_vm,
        w_cor, b_cor, w_cat, b_cat,
        u_upd, w_upd, b_upd, u_rst, w_rst, b_rst,
        (float*)d_out);
}

// Round 3
// 8240.801 us; speedup vs baseline: 1.2907x; 1.2907x over previous
//
#include <hip/hip_runtime.h>
#include <stdint.h>

// PaddGRULayer: B=256, T=512, F=64, U=128. fp32 in/out.
// One persistent block per batch row (256 blocks x 512 threads, 1 block/CU).
// Weights register-resident as packed bf16 pairs (~136 u32/thread, no spill);
// state fp32 in LDS. 512 threads => deeper K-splits vs round-2's 256.

#define T_STEPS 512
#define BDIM 512

typedef unsigned int u32;
typedef unsigned short u16;

__device__ __forceinline__ u16 f2bf(float f) {
    u32 u = __float_as_uint(f);
    u32 r = (u + 0x7fffu + ((u >> 16) & 1u)) >> 16;  // RNE
    return (u16)r;
}
__device__ __forceinline__ u32 pack2(float a, float b) {
    return (u32)f2bf(a) | ((u32)f2bf(b) << 16);
}
__device__ __forceinline__ float lo_f(u32 u) { return __uint_as_float(u << 16); }
__device__ __forceinline__ float hi_f(u32 u) { return __uint_as_float(u & 0xffff0000u); }
__device__ __forceinline__ float sigm(float x) { return 1.0f / (1.0f + __expf(-x)); }
__device__ __forceinline__ float tanh_f(float x) { return 2.0f / (1.0f + __expf(-2.0f * x)) - 1.0f; }

__global__ __launch_bounds__(BDIM, 2)
void padd_gru_kernel(
    const float* __restrict__ xin,                       // [256,512,320]
    const float* __restrict__ h0,                        // [256,128]
    const float* __restrict__ ts0,                       // [256,64]
    const float* __restrict__ dt0,                       // [256,64]
    const float* __restrict__ w_reg, const float* __restrict__ b_reg,   // [128,64],[1]
    const float* __restrict__ w_ctl, const float* __restrict__ b_ctl,   // [128,64],[64]
    const float* __restrict__ w_dlt, const float* __restrict__ b_dlt,   // [64,128],[1]
    const float* __restrict__ w_vm,  const float* __restrict__ b_vm,    // [128,128],[1]
    const float* __restrict__ w_cor, const float* __restrict__ b_cor,   // [64,64],[64]
    const float* __restrict__ w_cat, const float* __restrict__ b_cat,   // [192,64],[1]
    const float* __restrict__ u_upd, const float* __restrict__ w_upd, const float* __restrict__ b_upd, // [128,128]x2,[1]
    const float* __restrict__ u_rst, const float* __restrict__ w_rst, const float* __restrict__ b_rst, // [128,128]x2,[1]
    float* __restrict__ out)
{
    const int t = threadIdx.x;
    const int b = blockIdx.x;

    __shared__ float h32[128];
    __shared__ float outbuf[320];   // [xreg(64) | zcorr(64) | c(64) | ts(64) | dt(64)] = output row order
    __shared__ float tv32[64];
    __shared__ float xcur32[64];
    __shared__ float cat32[192];    // [m(64) | decay(128)]  (stage D input)
    __shared__ float inE32[256];    // [dh(128) | c(64) | m(64)]  (stage E input)
    __shared__ float rdh32[128];
    __shared__ float red[512];
    __shared__ float red2[512];
    __shared__ float xs[320];
    __shared__ float bctl32[64];
    __shared__ float bcor32[64];

    const int jA = t & 127, sA = t >> 7;   // stages A/C1/F: col jA, 4-way K-split (sA wave-uniform)
    const int j8 = t & 63,  s8 = t >> 6;   // stages C2/D: col j8, 8-way K-split (s8 wave-uniform)
    const int jE = t & 255, sE = t >> 8;   // stage E: col jE, 2-way K-split (sE wave-uniform)

    // -------- register-resident packed-bf16 weights (converted from fp32) --------
    u32 wA[16];    // [w_reg | w_ctl] col jA, k in [32*sA, +32)
    u32 wD[8];     // w_delta col jA, k in [16*sA, +16)
    u32 wC[4];     // w_corr (diag-masked) col j8, k in [8*s8, +8)
    u32 wCt[12];   // w_concat col j8, k in [24*s8, +24)
    u32 wE[64];    // col jE of [[u_upd,u_rst],[w_upd,w_rst]]: sE=0 -> u-part, sE=1 -> w-part (K=128 each)
    u32 wF[32];    // col jA of [u_upd ; w_value_mask] (K=256), k in [64*sA, +64)

    {
        const float* src = (jA < 64) ? (w_reg + jA) : (w_ctl + (jA - 64));
        #pragma unroll
        for (int i = 0; i < 16; i++) {
            int k = 32 * sA + 2 * i;
            wA[i] = pack2(src[k * 64], src[(k + 1) * 64]);
        }
    }
    {
        #pragma unroll
        for (int i = 0; i < 8; i++) {
            int k = 16 * sA + 2 * i;
            wD[i] = pack2(w_dlt[k * 128 + jA], w_dlt[(k + 1) * 128 + jA]);
        }
    }
    {
        #pragma unroll
        for (int i = 0; i < 4; i++) {
            int k = 8 * s8 + 2 * i;
            float a = (k     == j8) ? 0.f : w_cor[k * 64 + j8];
            float c = (k + 1 == j8) ? 0.f : w_cor[(k + 1) * 64 + j8];
            wC[i] = pack2(a, c);
        }
    }
    {
        #pragma unroll
        for (int i = 0; i < 12; i++) {
            int k = 24 * s8 + 2 * i;
            wCt[i] = pack2(w_cat[k * 64 + j8], w_cat[(k + 1) * 64 + j8]);
        }
    }
    {
        // stage E matrix: rows = [u_*(128) ; w_*(128)], cols = [upd(128) | rst(128)]
        const float* M = (jE < 128) ? (sE == 0 ? u_upd : w_upd)
                                    : (sE == 0 ? u_rst : w_rst);
        const float* src = M + (jE & 127);
        #pragma unroll
        for (int i = 0; i < 64; i++) {
            wE[i] = pack2(src[(2 * i) * 128], src[(2 * i + 1) * 128]);
        }
    }
    {
        // stage F matrix: rows = [u_upd(128) ; w_vm(128)], col jA, k in [64*sA,+64)
        const float* base = (sA < 2) ? (u_upd + (64 * sA) * 128 + jA)
                                     : (w_vm + (64 * (sA - 2)) * 128 + jA);
        #pragma unroll
        for (int i = 0; i < 32; i++) {
            wF[i] = pack2(base[(2 * i) * 128], base[(2 * i + 1) * 128]);
        }
    }

    const float bReg = b_reg[0];
    const float bDlt = b_dlt[0];
    const float bVm  = b_vm[0];
    const float bCat = b_cat[0];
    const float bUpd = b_upd[0];
    const float bRst = b_rst[0];

    if (t < 128) h32[t] = h0[(size_t)b * 128 + t];
    if (t < 64) {
        outbuf[192 + t] = ts0[(size_t)b * 64 + t];
        outbuf[256 + t] = dt0[(size_t)b * 64 + t];
        bctl32[t] = b_ctl[t];
        bcor32[t] = b_cor[t];
    }
    __syncthreads();

    float zloc = 0.0f;  // z gate, persists E-combine -> F-combine (same thread t<128)

    for (int st = 0; st < T_STEPS; ++st) {
        // input row -> LDS (coalesced float2 loads)
        {
            const float2* xr = (const float2*)(xin + ((size_t)b * 512 + st) * 320);
            if (t < 160) {
                float2 v = xr[t];
                xs[2 * t]     = v.x;
                xs[2 * t + 1] = v.y;
            }
        }

        // ---- stage A: h @ [w_reg | w_ctl]  (K=128 -> N=128, 4-way k-split)
        {
            float a0 = 0.f, a1 = 0.f;
            const float* hp = &h32[32 * sA];
            #pragma unroll
            for (int i = 0; i < 16; i++) {
                u32 u = wA[i];
                a0 = fmaf(lo_f(u), hp[2 * i],     a0);
                a1 = fmaf(hi_f(u), hp[2 * i + 1], a1);
            }
            red[t] = a0 + a1;
        }
        __syncthreads();  // B1
        if (t < 128) {
            float s = red[t] + red[t + 128] + red[t + 256] + red[t + 384];
            if (t < 64) outbuf[t] = s + bReg;                     // x_reg
            else        tv32[t - 64] = fabsf(s + bctl32[t - 64]); // tv
        }
        __syncthreads();  // B2

        // ---- phase 2: elementwise ti/dt/x_cur (t<64)
        if (t < 64) {
            float ti_in = xs[t], x_in = xs[64 + t], m = xs[128 + t];
            float dt_in = xs[192 + t], pad = xs[256 + t];
            float pts = outbuf[192 + t], pdt = outbuf[256 + t];
            float tv = tv32[t], xrg = outbuf[t];
            float s   = pts + tv;
            float tic = pad * ti_in + (1.f - pad) * s;
            float tin = (tic <= 100.0f) ? tic : pts;
            float dg  = (s <= 100.0f) ? tv : pdt;
            float dtn = pad * dt_in + (1.f - pad) * dg;
            float xc  = m * x_in + (1.f - m) * xrg;
            outbuf[192 + t] = tin;   // ts (also output slice 3)
            outbuf[256 + t] = dtn;   // dt (also output slice 4)
            xcur32[t] = xc;
            cat32[t] = m;
            inE32[192 + t] = m;
        }
        __syncthreads();  // B3

        // ---- stage C: decay-pre (dt @ w_delta, 4-way) and z_corr (x_cur @ w_corr_masked, 8-way)
        {
            float a0 = 0.f, a1 = 0.f;
            const float* dp = &outbuf[256 + 16 * sA];
            #pragma unroll
            for (int i = 0; i < 8; i++) {
                u32 u = wD[i];
                a0 = fmaf(lo_f(u), dp[2 * i],     a0);
                a1 = fmaf(hi_f(u), dp[2 * i + 1], a1);
            }
            red[t] = a0 + a1;
            float c0 = 0.f, c1 = 0.f;
            const float* xp = &xcur32[8 * s8];
            #pragma unroll
            for (int i = 0; i < 4; i++) {
                u32 u = wC[i];
                c0 = fmaf(lo_f(u), xp[2 * i],     c0);
                c1 = fmaf(hi_f(u), xp[2 * i + 1], c1);
            }
            red2[t] = c0 + c1;
        }
        __syncthreads();  // B4
        if (t < 128) {
            float pre = red[t] + red[t + 128] + red[t + 256] + red[t + 384] + bDlt;
            float d = __expf(-fmaxf(pre, 0.f));     // decay
            cat32[64 + t] = d;
            inE32[t] = d * h32[t];                  // dh
            if (t < 64) {
                float zc = red2[t] + red2[64 + t] + red2[128 + t] + red2[192 + t]
                         + red2[256 + t] + red2[320 + t] + red2[384 + t] + red2[448 + t]
                         + bcor32[t];
                outbuf[64 + t] = zc;                // z_corr
            }
        }
        __syncthreads();  // B5

        // ---- stage D: beta-pre = [m, decay] @ w_concat (K=192 -> N=64, 8-way split)
        {
            float a0 = 0.f, a1 = 0.f;
            const float* cp = &cat32[24 * s8];
            #pragma unroll
            for (int i = 0; i < 12; i++) {
                u32 u = wCt[i];
                a0 = fmaf(lo_f(u), cp[2 * i],     a0);
                a1 = fmaf(hi_f(u), cp[2 * i + 1], a1);
            }
            red[t] = a0 + a1;
        }
        __syncthreads();  // B6
        if (t < 64) {
            float pre = red[t] + red[64 + t] + red[128 + t] + red[192 + t]
                      + red[256 + t] + red[320 + t] + red[384 + t] + red[448 + t]
                      + bCat;
            float beta = sigm(pre);
            float ct   = beta * outbuf[64 + t] + (1.f - beta) * outbuf[t];
            float m    = inE32[192 + t];
            float c    = m * xcur32[t] + (1.f - m) * ct;
            outbuf[128 + t] = c;
            inE32[128 + t]  = c;
        }
        __syncthreads();  // B7

        // ---- stage E: [dh|c|m](256) @ [[u_upd,u_rst],[w_upd,w_rst]]  (N=256, 2-way k-split)
        {
            float a0 = 0.f, a1 = 0.f, a2 = 0.f, a3 = 0.f;
            const float* ep = &inE32[128 * sE];
            #pragma unroll
            for (int i = 0; i < 64; i += 2) {
                u32 u = wE[i], v = wE[i + 1];
                a0 = fmaf(lo_f(u), ep[2 * i],     a0);
                a1 = fmaf(hi_f(u), ep[2 * i + 1], a1);
                a2 = fmaf(lo_f(v), ep[2 * i + 2], a2);
                a3 = fmaf(hi_f(v), ep[2 * i + 3], a3);
            }
            red[t] = (a0 + a1) + (a2 + a3);
        }
        __syncthreads();  // B8
        // ---- E combine: z (kept in reg, t<128), r -> r*dh (t in [128,256)); plus output row store
        if (t < 256) {
            float val = red[t] + red[t + 256];
            if (t < 128) {
                zloc = sigm(val + bUpd);
            } else {
                float r = sigm(val + bRst);
                rdh32[t - 128] = r * inE32[t - 128];
            }
        }
        if (t < 160) {
            float2 v;
            v.x = outbuf[2 * t];
            v.y = outbuf[2 * t + 1];
            float2* orow = (float2*)(out + ((size_t)st * 256 + b) * 320);
            orow[t] = v;
        }
        __syncthreads();  // B9

        // ---- stage F: [r*dh | c | m](256) @ [u_upd ; w_value_mask] (N=128, 4-way k-split)
        {
            float a0 = 0.f, a1 = 0.f;
            const float* fp = (sA < 2) ? (rdh32 + 64 * sA) : (inE32 + 64 * sA);
            #pragma unroll
            for (int i = 0; i < 32; i++) {
                u32 u = wF[i];
                a0 = fmaf(lo_f(u), fp[2 * i],     a0);
                a1 = fmaf(hi_f(u), fp[2 * i + 1], a1);
            }
            red[t] = a0 + a1;
        }
        __syncthreads();  // B10
        if (t < 128) {
            float hh = tanh_f(red[t] + red[t + 128] + red[t + 256] + red[t + 384] + bVm);
            h32[t] = (1.f - zloc) * h32[t] + zloc * hh;
        }
        __syncthreads();  // B11
    }

    // final carry outputs: hT, tsT, dtT
    if (t < 128) out[(size_t)41943040u + (size_t)b * 128 + t] = h32[t];
    if (t < 64) {
        out[(size_t)41975808u + (size_t)b * 64 + t] = outbuf[192 + t];
        out[(size_t)41992192u + (size_t)b * 64 + t] = outbuf[256 + t];
    }
}

extern "C" void kernel_launch(void* const* d_in, const int* in_sizes, int n_in,
                              void* d_out, int out_size, void* d_ws, size_t ws_size,
                              hipStream_t stream) {
    const float* xin   = (const float*)d_in[0];
    const float* h0    = (const float*)d_in[1];
    const float* ts0   = (const float*)d_in[2];
    const float* dt0   = (const float*)d_in[3];
    const float* w_reg = (const float*)d_in[4];
    const float* b_reg = (const float*)d_in[5];
    const float* w_ctl = (const float*)d_in[6];
    const float* b_ctl = (const float*)d_in[7];
    const float* w_dlt = (const float*)d_in[8];
    const float* b_dlt = (const float*)d_in[9];
    const float* w_vm  = (const float*)d_in[10];
    const float* b_vm  = (const float*)d_in[11];
    const float* w_cor = (const float*)d_in[12];
    const float* b_cor = (const float*)d_in[13];
    const float* w_cat = (const float*)d_in[14];
    const float* b_cat = (const float*)d_in[15];
    const float* u_upd = (const float*)d_in[16];
    const float* w_upd = (const float*)d_in[17];
    const float* b_upd = (const float*)d_in[18];
    const float* u_rst = (const float*)d_in[19];
    const float* w_rst = (const float*)d_in[20];
    const float* b_rst = (const float*)d_in[21];

    padd_gru_kernel<<<dim3(256), dim3(BDIM), 0, stream>>>(
        xin, h0, ts0, dt0,
        w_reg, b_reg, w_ctl, b_ctl, w_dlt, b_dlt, w_vm, b_vm,
        w_cor, b_cor, w_cat, b_cat,
        u_upd, w_upd, b_upd, u_rst, w_rst, b_rst,
        (float*)d_out);
}